// Round 2
// baseline (779.184 us; speedup 1.0000x reference)
//
#include <hip/hip_runtime.h>

// NonLocalBlock3D, fp32 in/out.
// B=2, C=128, IC=64, W=H=32, Z=128, NZ=64. n_pixels = B*W*H = 2048.
// One workgroup (256 threads) per pixel; conv phases split over two z-halves
// so the staged x tile (128c x 64z fp32 = 32 KB) fits LDS.

#define C_      128
#define IC_     64
#define Z_      128
#define NZ_     64
#define HZ_     64        // z elements per staging pass
#define CSTRIDE 131072    // W*H*Z elements between consecutive channels
#define NPIX    2048

__global__ __launch_bounds__(256) void nlb_kernel(
    const float* __restrict__ x,
    const float* __restrict__ g_w,    const float* __restrict__ g_b,
    const float* __restrict__ theta_w,const float* __restrict__ theta_b,
    const float* __restrict__ phi_w,  const float* __restrict__ phi_b,
    const float* __restrict__ cat_w,
    const float* __restrict__ W_w,    const float* __restrict__ W_b,
    const float* __restrict__ bn_g,   const float* __restrict__ bn_b,
    const float* __restrict__ bn_m,   const float* __restrict__ bn_v,
    float* __restrict__ out)
{
    const int tid = threadIdx.x;
    const int pix = blockIdx.x;          // 0..2047
    const int b   = pix >> 10;           // / (W*H)
    const int wh  = pix & 1023;
    const size_t base = (size_t)b * C_ * CSTRIDE + (size_t)wh * Z_;

    __shared__ __align__(16) float xs[C_ * HZ_];   // 32 KB; reused as ys[128][64]
    __shared__ float gT[NZ_ * 65];                 // gT[j*65 + oc], padded
    __shared__ float a_s[Z_];
    __shared__ float b_s[NZ_];
    __shared__ float tw_s[C_];
    __shared__ float alpha_s[C_], beta_s[C_];
    __shared__ float tb_s;

    // ---------------- Phase 0: per-channel prep ----------------------------
    if (tid < C_) {
        const int c = tid;
        float s = 0.f;
        for (int oc = 0; oc < IC_; ++oc)
            s += cat_w[oc] * theta_w[oc * C_ + c];
        tw_s[c] = s;                                   // collapsed theta weights
        const float sc = bn_g[c] / sqrtf(bn_v[c] + 1e-5f);
        alpha_s[c] = sc;
        beta_s[c]  = (W_b[c] - bn_m[c]) * sc + bn_b[c];
    }
    if (tid < NZ_) b_s[tid] = 0.f;
    if (tid == 255) {
        float s = 0.f;
        for (int oc = 0; oc < IC_; ++oc) s += cat_w[oc] * theta_b[oc];
        tb_s = s;
    }

    // ---------------- Conv passes over two z-halves ------------------------
    for (int h = 0; h < 2; ++h) {
        // stage x[:, h*64 .. h*64+63] into LDS (2048 float4 loads)
        for (int v = tid; v < 2048; v += 256) {
            const int c  = v >> 4;
            const int zq = (v & 15) << 2;
            *(float4*)&xs[c * HZ_ + zq] =
                *(const float4*)&x[base + (size_t)c * CSTRIDE + h * HZ_ + zq];
        }
        __syncthreads();   // xs ready (and, for h=0, phase-0 LDS data ready)

        // a_i = tw . x[:,i] + tb  (i in this half)
        if (tid < HZ_) {
            const int i = tid;
            float s = tb_s;
            for (int c = 0; c < C_; ++c)
                s += tw_s[c] * xs[c * HZ_ + i];
            a_s[h * HZ_ + i] = s;
        }

        // phi & g convs + z-pool for this half.
        // 1024 items: oc (64) x q (16 z-quads); z_local = 4q..4q+3.
        for (int e = tid; e < 1024; e += 256) {
            const int oc = e >> 4;           // wave-uniform within 16-lane groups
            const int q  = e & 15;
            const float pb = phi_b[oc], gb = g_b[oc];
            float p0 = pb, p1 = pb, p2 = pb, p3 = pb;
            float q0 = gb, q1 = gb, q2 = gb, q3 = gb;
            const float* pw = phi_w + oc * C_;
            const float* gw = g_w   + oc * C_;
            const float* xq = xs + (q << 2);
            for (int c4 = 0; c4 < 32; ++c4) {
                const float4 wp = *(const float4*)&pw[c4 << 2];
                const float4 wg = *(const float4*)&gw[c4 << 2];
                const float wpv[4] = {wp.x, wp.y, wp.z, wp.w};
                const float wgv[4] = {wg.x, wg.y, wg.z, wg.w};
                #pragma unroll
                for (int u = 0; u < 4; ++u) {
                    const float4 xv = *(const float4*)&xq[((c4 << 2) + u) * HZ_];
                    p0 += wpv[u] * xv.x; p1 += wpv[u] * xv.y;
                    p2 += wpv[u] * xv.z; p3 += wpv[u] * xv.w;
                    q0 += wgv[u] * xv.x; q1 += wgv[u] * xv.y;
                    q2 += wgv[u] * xv.z; q3 += wgv[u] * xv.w;
                }
            }
            // pool pairs (4q,4q+1)->j=2q and (4q+2,4q+3)->j=2q+1 (j local to half)
            const int jg = (h << 5) + (q << 1);
            const float cw = cat_w[IC_ + oc];
            atomicAdd(&b_s[jg],     cw * fmaxf(p0, p1));
            atomicAdd(&b_s[jg + 1], cw * fmaxf(p2, p3));
            gT[jg * 65 + oc]       = fmaxf(q0, q1);
            gT[(jg + 1) * 65 + oc] = fmaxf(q2, q3);
        }
        __syncthreads();   // conv reads of xs done before next stage / reuse
    }

    // ---------------- Phase 4: y[i][c'] = sum_j relu(a_i+b_j)/64 * gT[j][c']
    float* ys = (float*)xs;   // reuse 32 KB (all xs reads done)
    {
        const int i  = tid & 127;
        const int ch = tid >> 7;        // wave-uniform
        float acc[32];
        #pragma unroll
        for (int k = 0; k < 32; ++k) acc[k] = 0.f;
        const float ai = a_s[i];
        for (int j = 0; j < NZ_; ++j) {
            const float fij = fmaxf(ai + b_s[j], 0.f) * (1.0f / 64.0f);
            const float* grow = &gT[j * 65 + ch * 32];   // wave-uniform broadcast
            #pragma unroll
            for (int k = 0; k < 32; ++k) acc[k] += fij * grow[k];
        }
        // swizzled write: granule gg (channels 4gg..4gg+3) at col ((gg+i)&15)*4
        const int gbase = ch * 8;
        #pragma unroll
        for (int g = 0; g < 8; ++g) {
            const int gg = gbase + g;
            float4 v = make_float4(acc[g*4], acc[g*4+1], acc[g*4+2], acc[g*4+3]);
            *(float4*)&ys[i * 64 + (((gg + i) & 15) << 2)] = v;
        }
    }
    __syncthreads();

    // ---------------- Phase 5: out[c][i] = BN(W_w[c].y[i] + W_b[c]) + x[c][i]
    {
        const int i  = tid & 127;       // lane-varying -> coalesced global access
        const int ch = tid >> 7;        // wave-uniform
        float y[64];
        #pragma unroll
        for (int g = 0; g < 16; ++g) {
            float4 v = *(const float4*)&ys[i * 64 + (((g + i) & 15) << 2)];
            y[4*g] = v.x; y[4*g+1] = v.y; y[4*g+2] = v.z; y[4*g+3] = v.w;
        }
        const size_t colbase = base + i;
        for (int cc = 0; cc < 64; ++cc) {
            const int c = ch * 64 + cc;                 // wave-uniform
            const float* wrow = W_w + c * IC_;
            float acc = 0.f;
            #pragma unroll
            for (int g4 = 0; g4 < 16; ++g4) {
                const float4 wv = *(const float4*)&wrow[g4 << 2];  // wave-uniform
                acc += wv.x * y[4*g4] + wv.y * y[4*g4+1]
                     + wv.z * y[4*g4+2] + wv.w * y[4*g4+3];
            }
            const size_t gaddr = colbase + (size_t)c * CSTRIDE;
            out[gaddr] = acc * alpha_s[c] + beta_s[c] + x[gaddr];
        }
    }
}

extern "C" void kernel_launch(void* const* d_in, const int* in_sizes, int n_in,
                              void* d_out, int out_size, void* d_ws, size_t ws_size,
                              hipStream_t stream) {
    const float* x       = (const float*)d_in[0];
    const float* g_w     = (const float*)d_in[1];
    const float* g_b     = (const float*)d_in[2];
    const float* theta_w = (const float*)d_in[3];
    const float* theta_b = (const float*)d_in[4];
    const float* phi_w   = (const float*)d_in[5];
    const float* phi_b   = (const float*)d_in[6];
    const float* cat_w   = (const float*)d_in[7];
    const float* W_w     = (const float*)d_in[8];
    const float* W_b     = (const float*)d_in[9];
    const float* bn_g    = (const float*)d_in[10];
    const float* bn_b    = (const float*)d_in[11];
    const float* bn_m    = (const float*)d_in[12];
    const float* bn_v    = (const float*)d_in[13];
    float* out = (float*)d_out;

    nlb_kernel<<<dim3(NPIX), dim3(256), 0, stream>>>(
        x, g_w, g_b, theta_w, theta_b, phi_w, phi_b, cat_w,
        W_w, W_b, bn_g, bn_b, bn_m, bn_v, out);
}

// Round 3
// 339.827 us; speedup vs baseline: 2.2929x; 2.2929x over previous
//
#include <hip/hip_runtime.h>
#include <hip/hip_bf16.h>

// NonLocalBlock3D, fp32 in/out, bf16 MFMA compute.
// B=2, C=128, IC=64, W=H=32, Z=128, NZ=64. n_pixels = 2048.
// prep kernel: fold BN/theta, convert weights to bf16 in d_ws.
// main kernel: 1 pixel per 256-thread block (4 waves), 3 GEMM phases on
// mfma_f32_16x16x32_bf16. LDS 48.1 KB -> 3 blocks/CU.

#define C_      128
#define IC_     64
#define Z_      128
#define NZ_     64
#define CSTRIDE 131072
#define NPIX    2048

typedef __attribute__((ext_vector_type(8))) short short8;   // 8 bf16 (4 VGPRs)
typedef __attribute__((ext_vector_type(4))) float f32x4;

union S8 { short8 s; uint4 u4; unsigned short h[8]; };

__device__ __forceinline__ unsigned short f2b(float f) {
    union { __hip_bfloat16 h; unsigned short u; } cv;
    cv.h = __float2bfloat16(f);
    return cv.u;
}
__device__ __forceinline__ float b2f(unsigned short u) {
    union { float f; unsigned int i; } cv; cv.i = ((unsigned int)u) << 16; return cv.f;
}

// ---------------------------------------------------------------------------
// Prep: weights -> bf16 in ws; fold BN into alpha/beta; collapse theta via cat_w.
__global__ void nlb_prep(
    const float* __restrict__ g_w,   const float* __restrict__ theta_w,
    const float* __restrict__ phi_w, const float* __restrict__ W_w,
    const float* __restrict__ g_b,   const float* __restrict__ theta_b,
    const float* __restrict__ phi_b, const float* __restrict__ cat_w,
    const float* __restrict__ W_b,   const float* __restrict__ bn_g,
    const float* __restrict__ bn_b,  const float* __restrict__ bn_m,
    const float* __restrict__ bn_v,
    unsigned short* __restrict__ wcat, unsigned short* __restrict__ Wwb,
    float* __restrict__ twp, float* __restrict__ alphap, float* __restrict__ betap,
    float* __restrict__ cbp, float* __restrict__ cw2p, float* __restrict__ tbp)
{
    const int t = threadIdx.x;
    for (int idx = t; idx < 128 * 128; idx += 256) {           // [oc 0..127][c]
        const int oc = idx >> 7, c = idx & 127;
        const float v = (oc < 64) ? g_w[oc * 128 + c] : phi_w[(oc - 64) * 128 + c];
        wcat[idx] = f2b(v);
    }
    for (int idx = t; idx < 128 * 64; idx += 256)              // [c][oc] same layout
        Wwb[idx] = f2b(W_w[idx]);
    if (t < 128) {
        float s = 0.f;
        for (int oc = 0; oc < 64; ++oc) s += cat_w[oc] * theta_w[oc * 128 + t];
        twp[t] = s;
        const float sc = bn_g[t] * rsqrtf(bn_v[t] + 1e-5f);
        alphap[t] = sc;
        betap[t]  = (W_b[t] - bn_m[t]) * sc + bn_b[t];
        cbp[t] = (t < 64) ? g_b[t] : phi_b[t - 64];
    }
    if (t < 64) cw2p[t] = cat_w[64 + t];
    if (t == 0) {
        float s = 0.f;
        for (int oc = 0; oc < 64; ++oc) s += cat_w[oc] * theta_b[oc];
        tbp[0] = s;
    }
}

// ---------------------------------------------------------------------------
__global__ __launch_bounds__(256, 3) void nlb_main(
    const float* __restrict__ x,
    const unsigned short* __restrict__ wcat,   // [128 oc][128 c] bf16 (g|phi)
    const unsigned short* __restrict__ Wwb,    // [128 c][64 oc] bf16
    const float* __restrict__ twp, const float* __restrict__ alphap,
    const float* __restrict__ betap, const float* __restrict__ cbp,
    const float* __restrict__ cw2p, const float* __restrict__ tbp,
    float* __restrict__ out)
{
    const int tid  = threadIdx.x;
    const int lane = tid & 63;
    const int wv   = tid >> 6;       // wave 0..3
    const int n16  = lane & 15;
    const int q    = lane >> 4;      // quad 0..3
    const int pix  = blockIdx.x;
    const int b    = pix >> 10;
    const int wh   = pix & 1023;
    const size_t base = (size_t)b * C_ * CSTRIDE + (size_t)wh * Z_;

    __shared__ unsigned short buf1[128 * 72]; // stage bf16 [c][64z+8] / ys bf16 [i][64oc+8]
    __shared__ unsigned short xT[64 * 136];   // [z-half 64][c 128+8] bf16
    __shared__ unsigned short gp[64 * 72];    // [oc 64][j 64+8] bf16 (pooled g, bias inside)
    __shared__ float a_s[128], b_s[64];
    __shared__ float alpha_s[128], beta_s[128], tw_s[128], cb_s[128], cw2_s[64];

    // ---- P0: small arrays from ws ----
    if (tid < 128) {
        alpha_s[tid] = alphap[tid]; beta_s[tid] = betap[tid];
        tw_s[tid] = twp[tid];       cb_s[tid] = cbp[tid];
        a_s[tid] = tbp[0];
    }
    if (tid < 64) cw2_s[tid] = cw2p[tid];

    auto STAGE = [&](int h) {       // global fp32 -> bf16 LDS [c][z-half]
        #pragma unroll
        for (int it = 0; it < 8; ++it) {
            const int idx = it * 256 + tid;
            const int c = idx >> 4, zq = idx & 15;
            const float4 v = *(const float4*)&x[base + (size_t)c * CSTRIDE + h * 64 + zq * 4];
            uint2 p;
            p.x = (unsigned)f2b(v.x) | ((unsigned)f2b(v.y) << 16);
            p.y = (unsigned)f2b(v.z) | ((unsigned)f2b(v.w) << 16);
            *(uint2*)&buf1[c * 72 + zq * 4] = p;
        }
    };
    auto GATHER = [&](int h) {      // transpose buf1 -> xT[z][c]; a_i partials
        const int z = tid & 63, cb0 = (tid >> 6) * 32;
        float pa = 0.f;
        #pragma unroll
        for (int it = 0; it < 4; ++it) {
            const int c0 = cb0 + it * 8;
            unsigned short vv[8];
            #pragma unroll
            for (int u = 0; u < 8; ++u) vv[u] = buf1[(c0 + u) * 72 + z];
            #pragma unroll
            for (int u = 0; u < 8; ++u) pa += tw_s[c0 + u] * b2f(vv[u]);
            uint4 dw;
            dw.x = (unsigned)vv[0] | ((unsigned)vv[1] << 16);
            dw.y = (unsigned)vv[2] | ((unsigned)vv[3] << 16);
            dw.z = (unsigned)vv[4] | ((unsigned)vv[5] << 16);
            dw.w = (unsigned)vv[6] | ((unsigned)vv[7] << 16);
            *(uint4*)&xT[z * 136 + c0] = dw;
        }
        atomicAdd(&a_s[h * 64 + z], pa);
    };
    auto PHASEA = [&](int h) {      // D[z][oc] = Wcat . x  (+bias), pool z-pairs in-register
        short8 af[4];
        const int zl = 16 * wv + n16;            // A: m=lane&15 -> z row
        #pragma unroll
        for (int k = 0; k < 4; ++k)
            af[k] = *(const short8*)&xT[zl * 136 + k * 32 + q * 8];
        float bsum0 = 0.f, bsum1 = 0.f;
        const int j0 = h * 32 + 8 * wv + 2 * q;  // pooled j for (reg0,1); +1 for (reg2,3)
        #pragma unroll
        for (int oct = 0; oct < 8; ++oct) {
            const int oc = oct * 16 + n16;       // B: n=lane&15 -> oc col
            const float bias = cb_s[oc];
            f32x4 acc = {bias, bias, bias, bias};
            const unsigned short* wrow = wcat + oc * 128;
            #pragma unroll
            for (int k = 0; k < 4; ++k) {
                const short8 bf = *(const short8*)&wrow[k * 32 + q * 8];
                acc = __builtin_amdgcn_mfma_f32_16x16x32_bf16(af[k], bf, acc, 0, 0, 0);
            }
            // rows = quad*4+reg -> regs (0,1) and (2,3) are consecutive z: pool free
            const float p0 = fmaxf(acc[0], acc[1]);
            const float p1 = fmaxf(acc[2], acc[3]);
            if (oct < 4) {                        // g half -> gp[oc][j]
                gp[oc * 72 + j0]     = f2b(p0);
                gp[oc * 72 + j0 + 1] = f2b(p1);
            } else {                              // phi half -> b_j partials
                const float cw = cw2_s[oc - 64];
                bsum0 += cw * p0; bsum1 += cw * p1;
            }
        }
        #pragma unroll
        for (int m = 1; m < 16; m <<= 1) {        // reduce over the 16 oc lanes
            bsum0 += __shfl_xor(bsum0, m);
            bsum1 += __shfl_xor(bsum1, m);
        }
        if (n16 == 0) b_s[j0]     = bsum0;        // each wave owns disjoint j
        if (n16 == 1) b_s[j0 + 1] = bsum1;
    };

    STAGE(0);
    __syncthreads();
    GATHER(0);
    __syncthreads();
    STAGE(1);        // global loads for h1 in flight while h0 MFMAs run
    PHASEA(0);
    __syncthreads();
    GATHER(1);
    __syncthreads();
    PHASEA(1);
    __syncthreads();  // a_s, b_s, gp complete

    // ---- Phase B: y[i][oc'] = sum_j relu(a_i+b_j)/64 * gp[j][oc'] ----
    {
        const int i0 = 32 * wv;
        short8 bfrag[4][2];
        #pragma unroll
        for (int nt = 0; nt < 4; ++nt)
            #pragma unroll
            for (int k = 0; k < 2; ++k)
                bfrag[nt][k] = *(const short8*)&gp[(nt * 16 + n16) * 72 + k * 32 + q * 8];
        float bv[2][8];
        #pragma unroll
        for (int k = 0; k < 2; ++k)
            #pragma unroll
            for (int jj = 0; jj < 8; ++jj)
                bv[k][jj] = b_s[k * 32 + q * 8 + jj];
        f32x4 acc[2][4];
        #pragma unroll
        for (int mt = 0; mt < 2; ++mt) {
            const float ai = a_s[i0 + mt * 16 + n16];
            #pragma unroll
            for (int nt = 0; nt < 4; ++nt) acc[mt][nt] = (f32x4){0.f, 0.f, 0.f, 0.f};
            #pragma unroll
            for (int k = 0; k < 2; ++k) {
                S8 fr;                                 // f in A-frag layout, on the fly
                #pragma unroll
                for (int jj = 0; jj < 8; ++jj)
                    fr.h[jj] = f2b(fmaxf(ai + bv[k][jj], 0.f) * 0.015625f);
                #pragma unroll
                for (int nt = 0; nt < 4; ++nt)
                    acc[mt][nt] = __builtin_amdgcn_mfma_f32_16x16x32_bf16(
                        fr.s, bfrag[nt][k], acc[mt][nt], 0, 0, 0);
            }
        }
        #pragma unroll
        for (int mt = 0; mt < 2; ++mt)                 // ys[i][oc] bf16 into buf1
            #pragma unroll
            for (int nt = 0; nt < 4; ++nt)
                #pragma unroll
                for (int r = 0; r < 4; ++r) {
                    const int i  = i0 + mt * 16 + q * 4 + r;
                    const int oc = nt * 16 + n16;
                    buf1[i * 72 + oc] = f2b(acc[mt][nt][r]);
                }
    }
    __syncthreads();

    // ---- Phase C: out[c][z] = alpha_c*(W . y[z]) + beta_c + x[c][z] ----
    {
        const int zt0 = 2 * wv;                        // wave's z ntiles
        short8 bC[2][2];
        #pragma unroll
        for (int zt = 0; zt < 2; ++zt)
            #pragma unroll
            for (int k = 0; k < 2; ++k) {
                const int z = (zt0 + zt) * 16 + n16;
                bC[zt][k] = *(const short8*)&buf1[z * 72 + k * 32 + q * 8];
            }
        #pragma unroll
        for (int mt = 0; mt < 8; ++mt) {
            short8 aC[2];
            const int ca = mt * 16 + n16;
            #pragma unroll
            for (int k = 0; k < 2; ++k)
                aC[k] = *(const short8*)&Wwb[ca * 64 + k * 32 + q * 8];
            float al[4], be[4];
            #pragma unroll
            for (int r = 0; r < 4; ++r) {
                const int cr = mt * 16 + q * 4 + r;
                al[r] = alpha_s[cr]; be[r] = beta_s[cr];
            }
            #pragma unroll
            for (int zt = 0; zt < 2; ++zt) {
                f32x4 acc = {0.f, 0.f, 0.f, 0.f};
                #pragma unroll
                for (int k = 0; k < 2; ++k)
                    acc = __builtin_amdgcn_mfma_f32_16x16x32_bf16(aC[k], bC[zt][k], acc, 0, 0, 0);
                const int z = (zt0 + zt) * 16 + n16;
                #pragma unroll
                for (int r = 0; r < 4; ++r) {
                    const int cr = mt * 16 + q * 4 + r;
                    const size_t gaddr = base + (size_t)cr * CSTRIDE + z;
                    out[gaddr] = acc[r] * al[r] + be[r] + x[gaddr];
                }
            }
        }
    }
}

// ---------------------------------------------------------------------------
extern "C" void kernel_launch(void* const* d_in, const int* in_sizes, int n_in,
                              void* d_out, int out_size, void* d_ws, size_t ws_size,
                              hipStream_t stream) {
    const float* x       = (const float*)d_in[0];
    const float* g_w     = (const float*)d_in[1];
    const float* g_b     = (const float*)d_in[2];
    const float* theta_w = (const float*)d_in[3];
    const float* theta_b = (const float*)d_in[4];
    const float* phi_w   = (const float*)d_in[5];
    const float* phi_b   = (const float*)d_in[6];
    const float* cat_w   = (const float*)d_in[7];
    const float* W_w     = (const float*)d_in[8];
    const float* W_b     = (const float*)d_in[9];
    const float* bn_g    = (const float*)d_in[10];
    const float* bn_b    = (const float*)d_in[11];
    const float* bn_m    = (const float*)d_in[12];
    const float* bn_v    = (const float*)d_in[13];
    float* out = (float*)d_out;

    char* ws = (char*)d_ws;     // needs ~52 KB of scratch
    unsigned short* wcat = (unsigned short*)ws;             // 32768 B
    unsigned short* Wwb  = (unsigned short*)(ws + 32768);   // 16384 B
    float* twp    = (float*)(ws + 49152);
    float* alphap = (float*)(ws + 49664);
    float* betap  = (float*)(ws + 50176);
    float* cbp    = (float*)(ws + 50688);
    float* cw2p   = (float*)(ws + 51200);
    float* tbp    = (float*)(ws + 51456);

    nlb_prep<<<dim3(1), dim3(256), 0, stream>>>(
        g_w, theta_w, phi_w, W_w, g_b, theta_b, phi_b, cat_w, W_b,
        bn_g, bn_b, bn_m, bn_v,
        wcat, Wwb, twp, alphap, betap, cbp, cw2p, tbp);

    nlb_main<<<dim3(NPIX), dim3(256), 0, stream>>>(
        x, wcat, Wwb, twp, alphap, betap, cbp, cw2p, tbp, out);
}